// Round 2
// baseline (152.250 us; speedup 1.0000x reference)
//
#include <hip/hip_runtime.h>
#include <stdint.h>

typedef _Float16 half8  __attribute__((ext_vector_type(8)));
typedef float    f32x4  __attribute__((ext_vector_type(4)));
typedef uint32_t u32x4  __attribute__((ext_vector_type(4)));

#define NPIX 61504   // 16 * 62 * 62
#define LPB  3844    // 62*62
#define FIN  288
#define NOUT 64
#define KSPL 72      // spline k-slices (288 feat * 8 coef / 32)
#define KTOT 81      // + 9 base slices (288 feat / 32)

// ---------------- prep: weights -> f16 B-fragments in ws ----------------
// frag (kt, nf, lane) at index ((kt*4+nf)*64 + lane), 8 halves each.
// spline part (kt<72): element j = spline_w[o][f][j] * scaler[o][f],
//   o = nf*16 + (lane&15), f = kt*4 + (lane>>4)
// base part (kt>=72): element j = base_w[o][f0+j], f0 = (kt-72)*32 + (lane>>4)*8
__global__ void prep_bfrag(const float* __restrict__ bw,
                           const float* __restrict__ sw,
                           const float* __restrict__ sc,
                           half8* __restrict__ bfrag) {
  int t = blockIdx.x * 256 + threadIdx.x;   // 0..20735
  half8 v;
  int dst;
  if (t < NOUT * FIN) {                     // 18432 spline (o,f) pairs
    int o = t / FIN;
    int f = t - o * FIN;
    float scale = sc[t];
    const float* p = sw + t * 8;            // contiguous 32B per thread
#pragma unroll
    for (int c = 0; c < 8; ++c) v[c] = (_Float16)(p[c] * scale);
    dst = (((f >> 2) * 4 + (o >> 4)) * 64) + ((f & 3) * 16) + (o & 15);
  } else {                                  // 2304 base frag-lanes
    int t2 = t - NOUT * FIN;
    int lane = t2 & 63;
    int nf = (t2 >> 6) & 3;
    int ktb = t2 >> 8;                      // 0..8
    int o = nf * 16 + (lane & 15);
    int f0 = ktb * 32 + (lane >> 4) * 8;
    const float* p = bw + o * FIN + f0;     // contiguous 32B
#pragma unroll
    for (int c = 0; c < 8; ++c) v[c] = (_Float16)p[c];
    dst = ((KSPL + ktb) * 4 + nf) * 64 + lane;
  }
  bfrag[dst] = v;
}

// ---------------- cubic B-spline basis: 8 slots, f16-packed ----------------
// grid = arange(-3,9)*0.4 - 1; u = (x+2.2)/0.4; interval i = floor(u);
// nonzero bases at slots i-3..i (clipped to [0,7]) with the standard uniform
// cubic weights. Funnel-shift scatter: V = [h(w0) h(w1) h(w2) h(w3)] (64b),
// pair q (slots 2q,2q+1) = 32 bits of V at byte offset 6-2d, d = i-2q.
// d outside [0,4] -> 0, which also covers x outside [-2.2, 2.2).
__device__ inline half8 bspline8(float xv) {
  float u = fmaf(xv, 2.5f, 5.5f);
  float fi = floorf(u);
  int i = (int)fi;
  float t = u - fi, s = 1.0f - t;
  float t2 = t * t, t3 = t2 * t;
  float s2 = s * s, s3 = s2 * s;
  float w3 = t3 * 0.16666667f;
  float w0 = s3 * 0.16666667f;
  float w1 = fmaf(0.5f, t3, -t2) + 0.66666667f;   // (3t^3-6t^2+4)/6
  float w2 = fmaf(0.5f, s3, -s2) + 0.66666667f;   // (3s^3-6s^2+4)/6
  uint32_t u01 = __builtin_bit_cast(uint32_t, __builtin_amdgcn_cvt_pkrtz(w0, w1));
  uint32_t u23 = __builtin_bit_cast(uint32_t, __builtin_amdgcn_cvt_pkrtz(w2, w3));
  uint64_t V = (uint64_t)u01 | ((uint64_t)u23 << 32);
  uint32_t vl = (uint32_t)(V << 16);
  u32x4 fr;
#pragma unroll
  for (int q = 0; q < 4; ++q) {
    int d = i - 2 * q;
    uint32_t rr = (uint32_t)(V >> ((48 - 16 * d) & 63));
    fr[q] = ((uint32_t)d <= 3u) ? rr : ((d == 4) ? vl : 0u);
  }
  return __builtin_bit_cast(half8, fr);
}

// ---------------- main: fused unfold + KAN linear via MFMA ----------------
// wave: 2 M-frags (32 pixels) x 4 N-frags (64 outs); block: 4 waves = 128 px.
__global__ __launch_bounds__(256, 2) void kan_main(
    const float* __restrict__ x,
    const half8* __restrict__ bfrag,
    float* __restrict__ out) {
  const int lane = threadIdx.x & 63;
  const int wv   = threadIdx.x >> 6;
  const int quad = lane >> 4;
  const int m16  = lane & 15;
  const int pixbase = blockIdx.x * 128 + wv * 32;

  // A-side pixel base addresses (row m = lane&15); clamp for tail
  int xbase[2];
#pragma unroll
  for (int mi = 0; mi < 2; ++mi) {
    uint32_t p = pixbase + mi * 16 + m16;
    if (p > NPIX - 1) p = NPIX - 1;
    uint32_t b = p / LPB;
    uint32_t l = p - b * LPB;
    uint32_t ho = l / 62u;
    uint32_t wo = l - ho * 62u;
    xbase[mi] = (int)(b * 131072u + ho * 64u + wo);  // x[b][0][ho][wo]
  }

  f32x4 acc[2][4];
#pragma unroll
  for (int mi = 0; mi < 2; ++mi)
#pragma unroll
    for (int nf = 0; nf < 4; ++nf)
      acc[mi][nf] = (f32x4){0.f, 0.f, 0.f, 0.f};

  // ---- spline K-slices: one basis eval per lane per A-frag ----
#pragma unroll 2
  for (int kt = 0; kt < KSPL; ++kt) {
    int f = kt * 4 + quad;                 // feature for this lane
    int c = (f * 57) >> 9;                 // f / 9
    int r = f - c * 9;
    int ii = (r * 11) >> 5;                // r / 3
    int jj = r - ii * 3;
    int xoff = c * 4096 + ii * 64 + jj;

    half8 bf[4];
#pragma unroll
    for (int nf = 0; nf < 4; ++nf)
      bf[nf] = bfrag[(kt * 4 + nf) * 64 + lane];

    half8 af[2];
#pragma unroll
    for (int mi = 0; mi < 2; ++mi)
      af[mi] = bspline8(x[xbase[mi] + xoff]);

#pragma unroll
    for (int nf = 0; nf < 4; ++nf)
#pragma unroll
      for (int mi = 0; mi < 2; ++mi)
        acc[mi][nf] = __builtin_amdgcn_mfma_f32_16x16x32_f16(
            af[mi], bf[nf], acc[mi][nf], 0, 0, 0);
  }

  // ---- base K-slices: relu(patch) ----
#pragma unroll 1
  for (int kt = KSPL; kt < KTOT; ++kt) {
    int f0 = (kt - KSPL) * 32 + quad * 8;
    int xoff[8];
#pragma unroll
    for (int j = 0; j < 8; ++j) {
      int f = f0 + j;
      int c = (f * 57) >> 9;
      int r = f - c * 9;
      int ii = (r * 11) >> 5;
      int jj = r - ii * 3;
      xoff[j] = c * 4096 + ii * 64 + jj;
    }
    half8 bf[4];
#pragma unroll
    for (int nf = 0; nf < 4; ++nf)
      bf[nf] = bfrag[(kt * 4 + nf) * 64 + lane];

    half8 af[2];
#pragma unroll
    for (int mi = 0; mi < 2; ++mi) {
      half8 a;
#pragma unroll
      for (int j = 0; j < 8; ++j)
        a[j] = (_Float16)fmaxf(x[xbase[mi] + xoff[j]], 0.0f);
      af[mi] = a;
    }
#pragma unroll
    for (int nf = 0; nf < 4; ++nf)
#pragma unroll
      for (int mi = 0; mi < 2; ++mi)
        acc[mi][nf] = __builtin_amdgcn_mfma_f32_16x16x32_f16(
            af[mi], bf[nf], acc[mi][nf], 0, 0, 0);
  }

  // ---- epilogue: C/D layout col(=out)=lane&15, row(=pixel)=quad*4+reg ----
#pragma unroll
  for (int mi = 0; mi < 2; ++mi) {
#pragma unroll
    for (int rg = 0; rg < 4; ++rg) {
      uint32_t p = pixbase + mi * 16 + quad * 4 + rg;
      bool ok = p < NPIX;
      uint32_t pc = ok ? p : (NPIX - 1);
      uint32_t b = pc / LPB;
      uint32_t l = pc - b * LPB;
      uint32_t obase = b * (NOUT * LPB) + l;   // out[b][o][ho][wo], o stride LPB
#pragma unroll
      for (int nf = 0; nf < 4; ++nf) {
        uint32_t o = nf * 16 + m16;
        if (ok) out[obase + o * LPB] = acc[mi][nf][rg];
      }
    }
  }
}

extern "C" void kernel_launch(void* const* d_in, const int* in_sizes, int n_in,
                              void* d_out, int out_size, void* d_ws, size_t ws_size,
                              hipStream_t stream) {
  const float* x  = (const float*)d_in[0];
  const float* bw = (const float*)d_in[1];  // (64, 288)
  const float* sw = (const float*)d_in[2];  // (64, 288, 8)
  const float* sc = (const float*)d_in[3];  // (64, 288)
  float* out = (float*)d_out;
  half8* bfrag = (half8*)d_ws;              // 20736 * 16B = 331,776 B

  prep_bfrag<<<81, 256, 0, stream>>>(bw, sw, sc, bfrag);
  const int nblk = (NPIX + 127) / 128;      // 481
  kan_main<<<nblk, 256, 0, stream>>>(x, bfrag, out);
}

// Round 3
// 121.279 us; speedup vs baseline: 1.2554x; 1.2554x over previous
//
#include <hip/hip_runtime.h>
#include <stdint.h>

typedef _Float16 half8  __attribute__((ext_vector_type(8)));
typedef float    f32x4  __attribute__((ext_vector_type(4)));
typedef uint32_t u32x4  __attribute__((ext_vector_type(4)));

#define FIN  288
#define NOUT 64
#define LPB  3844            // 62*62
#define KSPL 72
#define SC   200             // LDS channel stride (floats): 3*64 + 8 skew
#define LDSN (31*SC + 2*64 + 64 + 8)   // 6400 floats = 25.6 KB (+pad for OOB tail lanes)

// K-order permutation (spline part): kt = ii*24 + jj*8 + g, quad q -> channel
// c = 4g + q, feature f = 9c + 3ii + jj. Bijection over (q,g,ii,jj).
// LDS bank = (SC*c + wo + jj) % 32 = (8q + wo + jj) % 32 -> quads offset by 8
// banks => exact 2-way aliasing across the 64 lanes (free).

// ---------------- prep: weights -> f16 B-fragments in ws ----------------
__global__ void prep_bfrag(const float* __restrict__ bw,
                           const float* __restrict__ sw,
                           const float* __restrict__ sc,
                           half8* __restrict__ bfrag) {
  int t = blockIdx.x * 256 + threadIdx.x;   // 0..20735
  half8 v;
  int dst;
  if (t < NOUT * FIN) {                     // spline (o,f) pairs
    int o = t / FIN;
    int f = t - o * FIN;
    float scale = sc[t];
    const float* p = sw + t * 8;
#pragma unroll
    for (int c = 0; c < 8; ++c) v[c] = (_Float16)(p[c] * scale);
    int ch = f / 9;
    int r  = f - ch * 9;
    int ii = r / 3;
    int jj = r - ii * 3;
    int g  = ch >> 2, q = ch & 3;
    int kt = ii * 24 + jj * 8 + g;
    dst = (kt * 4 + (o >> 4)) * 64 + q * 16 + (o & 15);
  } else {                                  // base frag-lanes (natural K-order)
    int t2 = t - NOUT * FIN;
    int lane = t2 & 63;
    int nf = (t2 >> 6) & 3;
    int ktb = t2 >> 8;                      // 0..8
    int o = nf * 16 + (lane & 15);
    int f0 = ktb * 32 + (lane >> 4) * 8;
    const float* p = bw + o * FIN + f0;
#pragma unroll
    for (int c = 0; c < 8; ++c) v[c] = (_Float16)p[c];
    dst = ((KSPL + ktb) * 4 + nf) * 64 + lane;
  }
  bfrag[dst] = v;
}

// ---------------- cubic B-spline basis: 8 slots, f16-packed ----------------
__device__ inline half8 bspline8(float xv) {
  float u = fmaf(xv, 2.5f, 5.5f);
  float fi = floorf(u);
  int i = (int)fi;
  float t = u - fi, s = 1.0f - t;
  float t2 = t * t, t3 = t2 * t;
  float s2 = s * s, s3 = s2 * s;
  float w3 = t3 * 0.16666667f;
  float w0 = s3 * 0.16666667f;
  float w1 = fmaf(0.5f, t3, -t2) + 0.66666667f;
  float w2 = fmaf(0.5f, s3, -s2) + 0.66666667f;
  uint32_t u01 = __builtin_bit_cast(uint32_t, __builtin_amdgcn_cvt_pkrtz(w0, w1));
  uint32_t u23 = __builtin_bit_cast(uint32_t, __builtin_amdgcn_cvt_pkrtz(w2, w3));
  uint64_t V = (uint64_t)u01 | ((uint64_t)u23 << 32);
  uint32_t vl = (uint32_t)(V << 16);
  u32x4 fr;
#pragma unroll
  for (int q = 0; q < 4; ++q) {
    int d = i - 2 * q;
    uint32_t rr = (uint32_t)(V >> ((48 - 16 * d) & 63));
    fr[q] = ((uint32_t)d <= 3u) ? rr : ((d == 4) ? vl : 0u);
  }
  return __builtin_bit_cast(half8, fr);
}

// ---------------- main: one (b,ho) row per block; LDS-staged x ----------------
// block: 256 thr = 4 waves; wave = 16 pixels (wo = wv*16 + m16) x 64 outs.
__global__ __launch_bounds__(256, 4) void kan_main(
    const float* __restrict__ x,
    const half8* __restrict__ bfrag,
    float* __restrict__ out) {
  __shared__ float lx[LDSN];

  const int tid = threadIdx.x;
  const int bid = blockIdx.x;           // 0..991
  const int b  = bid / 62;
  const int ho = bid - b * 62;

  // ---- stage x tile: 32 ch x 3 rows x 64 cols, skewed stride SC ----
  const float* xb = x + b * 131072 + ho * 64;    // x[b][0][ho][0]
#pragma unroll
  for (int r = 0; r < 6; ++r) {
    int gid = r * 256 + tid;            // 0..1535 float4s
    int row = gid >> 4;                 // 0..95 = c*3+ii
    int c   = (row * 683) >> 11;        // row/3
    int ii  = row - c * 3;
    int colv = (gid & 15) * 4;
    const float4 v = *(const float4*)(xb + c * 4096 + ii * 64 + colv);
    *(float4*)(&lx[c * SC + ii * 64 + colv]) = v;
  }
  __syncthreads();

  const int lane = tid & 63;
  const int wv   = tid >> 6;
  const int quad = lane >> 4;
  const int m16  = lane & 15;
  const int wo   = wv * 16 + m16;       // 0..63 (>=62 lanes compute garbage, not stored)

  f32x4 acc[4];
#pragma unroll
  for (int nf = 0; nf < 4; ++nf) acc[nf] = (f32x4){0.f, 0.f, 0.f, 0.f};

  // ---- spline K-slices ----
  int kt = 0;
#pragma unroll
  for (int ii = 0; ii < 3; ++ii) {
#pragma unroll
    for (int jj = 0; jj < 3; ++jj) {
      const float* lbase = lx + quad * SC + ii * 64 + wo + jj;  // channel 4g+quad
#pragma unroll
      for (int g = 0; g < 8; ++g) {
        float xv = lbase[g * (4 * SC)];
        half8 af = bspline8(xv);
#pragma unroll
        for (int nf = 0; nf < 4; ++nf) {
          half8 bf = bfrag[(kt * 4 + nf) * 64 + lane];
          acc[nf] = __builtin_amdgcn_mfma_f32_16x16x32_f16(af, bf, acc[nf], 0, 0, 0);
        }
        ++kt;
      }
    }
  }

  // ---- base K-slices: relu(patch), natural feature order ----
#pragma unroll
  for (int kb = 0; kb < 9; ++kb) {
    int f0 = kb * 32 + quad * 8;
    half8 a;
#pragma unroll
    for (int j = 0; j < 8; ++j) {
      int f = f0 + j;
      int c = (f * 57) >> 9;            // f/9 for f<512
      int r = f - c * 9;
      int i2 = (r * 11) >> 5;           // r/3 for r<9
      int j2 = r - i2 * 3;
      a[j] = (_Float16)fmaxf(lx[c * SC + i2 * 64 + wo + j2], 0.0f);
    }
#pragma unroll
    for (int nf = 0; nf < 4; ++nf) {
      half8 bf = bfrag[((KSPL + kb) * 4 + nf) * 64 + lane];
      acc[nf] = __builtin_amdgcn_mfma_f32_16x16x32_f16(a, bf, acc[nf], 0, 0, 0);
    }
  }

  // ---- epilogue: C/D layout col(=out)=m16, row(=pixel)=quad*4+reg ----
  float* ob = out + b * (NOUT * LPB) + ho * 62;
#pragma unroll
  for (int rg = 0; rg < 4; ++rg) {
    int wo2 = wv * 16 + quad * 4 + rg;
    if (wo2 < 62) {
#pragma unroll
      for (int nf = 0; nf < 4; ++nf) {
        int o = nf * 16 + m16;
        ob[o * LPB + wo2] = acc[nf][rg];
      }
    }
  }
}

extern "C" void kernel_launch(void* const* d_in, const int* in_sizes, int n_in,
                              void* d_out, int out_size, void* d_ws, size_t ws_size,
                              hipStream_t stream) {
  const float* x  = (const float*)d_in[0];
  const float* bw = (const float*)d_in[1];  // (64, 288)
  const float* sw = (const float*)d_in[2];  // (64, 288, 8)
  const float* sc = (const float*)d_in[3];  // (64, 288)
  float* out = (float*)d_out;
  half8* bfrag = (half8*)d_ws;              // 20736 * 16B = 331,776 B

  prep_bfrag<<<81, 256, 0, stream>>>(bw, sw, sc, bfrag);
  kan_main<<<16 * 62, 256, 0, stream>>>(x, bfrag, out);
}